// Round 13
// baseline (1814.024 us; speedup 1.0000x reference)
//
#include <hip/hip_runtime.h>
#include <math.h>

#define NN 3072
#define EPSG 1e-20f
#define EDGE_CAP 53248          // ~47.2K expected edges + margin
#define RCH 128                 // rows per chunk
#define NCH 24                  // chunks (24*128 = 3072)
typedef unsigned long long u64;

// ---------- prep 1: rowsum0[i] = sum_c adj[i][c] ----------
__global__ __launch_bounds__(256) void rowsum_kernel(const float* __restrict__ adj,
                                                     float* __restrict__ rowsum) {
    int row = blockIdx.x;
    const float* r = adj + (size_t)row * NN;
    float s = 0.f;
    for (int c = threadIdx.x; c < NN; c += 256) s += r[c];
#pragma unroll
    for (int off = 32; off > 0; off >>= 1) s += __shfl_down(s, off);
    __shared__ float ps[4];
    if ((threadIdx.x & 63) == 0) ps[threadIdx.x >> 6] = s;
    __syncthreads();
    if (threadIdx.x == 0) rowsum[row] = (ps[0] + ps[1]) + (ps[2] + ps[3]);
}

// ---------- prep 2a: per-chunk column counts (288 blocks, coalesced) ----------
__global__ __launch_bounds__(256) void cnt_kernel(const float* __restrict__ adj,
                                                  unsigned* __restrict__ cnt) {
    int c = blockIdx.x * 256 + threadIdx.x;
    const float* col = adj + (size_t)(blockIdx.y * RCH) * NN + c;
    unsigned n = 0;
#pragma unroll 4
    for (int i = 0; i < RCH; ++i)
        n += (col[(size_t)i * NN] != 0.0f) ? 1u : 0u;
    cnt[blockIdx.y * NN + c] = n;
}

// ---------- prep 2b: total per-column counts ----------
__global__ __launch_bounds__(256) void colsum_kernel(const unsigned* __restrict__ cnt,
                                                     unsigned* __restrict__ colcnt) {
    int c = blockIdx.x * 256 + threadIdx.x;
    unsigned n = 0;
    for (int by = 0; by < NCH; ++by) n += cnt[by * NN + c];
    colcnt[c] = n;
}

// ---------- prep 2c: exclusive scan of column counts (1 wave) ----------
__global__ __launch_bounds__(64) void scan_kernel(const unsigned* __restrict__ colcnt,
                                                  unsigned* __restrict__ eoff) {
    int lane = threadIdx.x;
    unsigned tot = 0;
    for (int k = 0; k < 48; ++k) tot += colcnt[lane * 48 + k];
    unsigned x = tot;
    for (int off = 1; off < 64; off <<= 1) {
        unsigned y = __shfl_up(x, off);
        if (lane >= off) x += y;
    }
    unsigned run = x - tot;
    for (int k = 0; k < 48; ++k) {
        unsigned c = colcnt[lane * 48 + k];
        eoff[lane * 48 + k] = run;
        run += c;
    }
    if (lane == 63) eoff[NN] = run;
}

// ---------- prep 2d: per-(chunk,column) start offsets ----------
__global__ __launch_bounds__(256) void choff_kernel(const unsigned* __restrict__ cnt,
                                                    const unsigned* __restrict__ eoff,
                                                    unsigned* __restrict__ choff) {
    int c = blockIdx.x * 256 + threadIdx.x;
    unsigned run = eoff[c];
    for (int by = 0; by < NCH; ++by) {
        choff[by * NN + c] = run;
        run += cnt[by * NN + c];
    }
}

// ---------- prep 2e: fill CSC edge lists (288 blocks; ascending row order) ----------
__global__ __launch_bounds__(256) void fill2_kernel(const float* __restrict__ adj,
                                                    const unsigned* __restrict__ choff,
                                                    unsigned short* __restrict__ edges) {
    int c = blockIdx.x * 256 + threadIdx.x;
    int r0 = blockIdx.y * RCH;
    unsigned off = choff[blockIdx.y * NN + c];
    const float* col = adj + (size_t)r0 * NN + c;
    for (int i = 0; i < RCH; ++i) {
        if (col[(size_t)i * NN] != 0.0f) {
            if (off < EDGE_CAP) edges[off] = (unsigned short)(r0 + i);
            ++off;
        }
    }
}

// monotonic order-preserving float->u32 map (never 0 for finite inputs)
__device__ __forceinline__ unsigned enc32(float v) {
    unsigned u = __float_as_uint(v);
    return (u & 0x80000000u) ? ~u : (u | 0x80000000u);
}

// ---------- prep 3: gumbel + derived per-node arrays ----------
__global__ __launch_bounds__(256) void gumbel_kernel(const float* __restrict__ logits,
                                                     const float* __restrict__ unif,
                                                     const float* __restrict__ rowsum,
                                                     float* __restrict__ out,
                                                     float* __restrict__ elog,
                                                     unsigned* __restrict__ keyenc,
                                                     int* __restrict__ indeg) {
    int j = blockIdx.x * 256 + threadIdx.x;
    float lg = logits[j];
    float u  = unif[j];
    float g  = lg + (-logf(-logf(u + EPSG) + EPSG));
    out[NN + j] = g;                 // gumbel_logits output
    elog[j] = expf(lg);
    keyenc[j] = enc32(g);
    indeg[j] = (int)rowsum[j];
}

// DPP wave64 max-reduce: result valid in lane 63
__device__ __forceinline__ unsigned wmax_u32(unsigned v) {
    unsigned t;
    t = (unsigned)__builtin_amdgcn_update_dpp(0, (int)v, 0x111, 0xf, 0xf, true); v = t > v ? t : v;
    t = (unsigned)__builtin_amdgcn_update_dpp(0, (int)v, 0x112, 0xf, 0xf, true); v = t > v ? t : v;
    t = (unsigned)__builtin_amdgcn_update_dpp(0, (int)v, 0x114, 0xf, 0xf, true); v = t > v ? t : v;
    t = (unsigned)__builtin_amdgcn_update_dpp(0, (int)v, 0x118, 0xf, 0xf, true); v = t > v ? t : v;
    t = (unsigned)__builtin_amdgcn_update_dpp(0, (int)v, 0x142, 0xf, 0xf, true); v = t > v ? t : v;
    t = (unsigned)__builtin_amdgcn_update_dpp(0, (int)v, 0x143, 0xf, 0xf, true); v = t > v ? t : v;
    return v;
}
__device__ __forceinline__ float wsum_f32(float v) {
    int t;
    t = __builtin_amdgcn_update_dpp(0, __float_as_int(v), 0x111, 0xf, 0xf, true); v += __int_as_float(t);
    t = __builtin_amdgcn_update_dpp(0, __float_as_int(v), 0x112, 0xf, 0xf, true); v += __int_as_float(t);
    t = __builtin_amdgcn_update_dpp(0, __float_as_int(v), 0x114, 0xf, 0xf, true); v += __int_as_float(t);
    t = __builtin_amdgcn_update_dpp(0, __float_as_int(v), 0x118, 0xf, 0xf, true); v += __int_as_float(t);
    t = __builtin_amdgcn_update_dpp(0, __float_as_int(v), 0x142, 0xf, 0xf, true); v += __int_as_float(t);
    t = __builtin_amdgcn_update_dpp(0, __float_as_int(v), 0x143, 0xf, 0xf, true); v += __int_as_float(t);
    return v;
}
__device__ __forceinline__ int rdlane(int v, int l) { return __builtin_amdgcn_readlane(v, l); }
__device__ __forceinline__ u64 rdlane64(u64 v, int l) {
    unsigned lo = (unsigned)rdlane((int)(unsigned)v, l);
    unsigned hi = (unsigned)rdlane((int)(unsigned)(v >> 32), l);
    return ((u64)hi << 32) | lo;
}
__device__ __forceinline__ int div48(int j) { return ((j >> 4) * 21846) >> 16; }  // exact for j<3072

// ---------- sequential topo-sort: spec edge prefetch, u64 gather, background k2g ----------
__global__ __launch_bounds__(256) void topo_kernel(const float* __restrict__ elog_g,
                                                   const unsigned* __restrict__ keyenc_g,
                                                   const int* __restrict__ indeg_g,
                                                   const unsigned* __restrict__ eoff_g,
                                                   const unsigned short* __restrict__ edges_g,
                                                   float* __restrict__ gslog,
                                                   unsigned* __restrict__ gssel,
                                                   float* __restrict__ out) {
    __shared__ u64            s_keyind[NN + 8];         // lo=keyenc, hi=indeg (INF once selected)
    __shared__ float          s_elog[NN];
    __shared__ unsigned       s_meta[NN];               // eoff | d<<20
    __shared__ unsigned short s_edges[EDGE_CAP + 128];  // +pad for clamped reads

    const int tid = threadIdx.x;

    // ---- cooperative staging by all 4 waves ----
    for (int j = tid; j < NN; j += 256) {
        unsigned e0 = eoff_g[j];
        unsigned e1 = eoff_g[j + 1];
        s_keyind[j] = ((u64)(unsigned)indeg_g[j] << 32) | keyenc_g[j];
        s_elog[j] = elog_g[j];
        s_meta[j] = e0 | ((e1 - e0) << 20);
    }
    {
        unsigned total = eoff_g[NN];
        unsigned n32 = (total + 1) >> 1;
        unsigned cap32 = (EDGE_CAP + 128) / 2;
        if (n32 > cap32) n32 = cap32;
        for (unsigned x = tid; x < n32; x += 256)
            ((unsigned*)s_edges)[x] = ((const unsigned*)edges_g)[x];
    }
    __syncthreads();
    if (tid >= 64) return;              // wave 0 continues alone

    const int lane = tid;
    const int base48 = lane * 48;       // lane OWNS nodes [48l, 48l+48)

    // ---- init: exact top-2 per group; S over eligibles ----
    u64 key1 = 0ULL, key2 = 0ULL;
    float S;
    {
        unsigned b1 = 0u, b2 = 0u;
        int j1 = 0, j2i = 0;
        float ssl = 0.f;
        for (int i = 0; i < 48; ++i) {
            u64 nw = s_keyind[base48 + i];
            if ((unsigned)(nw >> 32) == 0u) {
                ssl += s_elog[base48 + i];
                unsigned e = (unsigned)nw;
                if (e > b1) { b2 = b1; j2i = j1; b1 = e; j1 = i; }
                else if (e > b2) { b2 = e; j2i = i; }
            }
        }
        if (b1) key1 = ((u64)b1 << 32) | (unsigned)(~(base48 + j1));
        if (b2) key2 = ((u64)b2 << 32) | (unsigned)(~(base48 + j2i));
        float tot = wsum_f32(ssl);
        S = __int_as_float(rdlane(__float_as_int(tot), 63));
    }

    // ---- initial tournament -> sel0; k2g; prime edge registers ----
    unsigned cur_sel;
    {
        unsigned vhi = (unsigned)(key1 >> 32);
        unsigned mx = (unsigned)rdlane((int)wmax_u32(vhi), 63);
        u64 ball = __ballot(vhi == mx);
        int gw = (int)__ffsll(ball) - 1;
        unsigned lo = (unsigned)rdlane((int)(unsigned)key1, gw);
        cur_sel = ~lo;
    }
    u64 k2g;
    {
        int gw = div48((int)cur_sel);
        unsigned re = (lane == gw) ? 0u : (unsigned)(key1 >> 32);
        unsigned mx = (unsigned)rdlane((int)wmax_u32(re), 63);
        u64 ball = __ballot(re == mx);
        int w = (int)__ffsll(ball) - 1;
        unsigned lo = (unsigned)rdlane((int)(unsigned)key1, w);
        u64 k2x = mx ? (((u64)mx << 32) | lo) : 0ULL;
        u64 k2b = rdlane64(key2, gw);
        k2g = k2x > k2b ? k2x : k2b;
    }
    int d, ew;
    float elog_sel;
    {
        unsigned m = s_meta[cur_sel];
        unsigned e0 = m & 0xFFFFFu;
        d = (int)(m >> 20);
        ew = (int)s_edges[e0 + (lane < d ? lane : 0)];
        elog_sel = s_elog[cur_sel];
    }

    for (int t = 0; t < NN; ++t) {
        const int sel = (int)cur_sel;       // uniform
        const int g = div48(sel);

        // ---- chain A: node gather for this column (issue FIRST) ----
        bool act = (lane < d);
        int j = act ? ew : 0;
        u64 nw = s_keyind[j];               // u64 gather (8 B)

        // ---- spec prefetch for next winner = k2g node (immutable arrays) ----
        unsigned spec = ~(unsigned)k2g;
        if (spec >= NN) spec = 0;
        unsigned mspec = s_meta[spec];      // uniform-addr broadcast
        unsigned e0s = mspec & 0xFFFFFu;
        int ds = (int)(mspec >> 20);
        int ews = (int)s_edges[e0s + (lane < ds ? lane : 0)];
        float elog_spec = s_elog[spec];

        // ---- record (global fire-and-forget) + mark selected ----
        if (lane == 0) {
            gslog[t] = S;
            gssel[t] = (unsigned)sel;
            ((unsigned*)&s_keyind[sel])[1] = 0xFFFFFFFFu;
        }

        // ---- substitution: winner group's new max = its exact 2nd (registers) ----
        bool isg = (lane == g);
        key1 = isg ? key2 : key1;
        key2 = isg ? 0ULL : key2;
        unsigned idx1 = ~(unsigned)rdlane((int)(unsigned)key1, g);
        u64 rn = s_keyind[g * 48 + (lane < 48 ? lane : 47)];   // rescan read

        // ---- consume gather: decrement + insertion detect ----
        unsigned hi = (unsigned)(nw >> 32);
        ((unsigned*)&s_keyind[act ? j : NN])[1] = hi - 1u;     // predicated dummy slot
        bool ins = act && (hi == 1u);
        u64 pend = ins ? (((nw & 0xFFFFFFFFULL) << 32) | (unsigned)(~j)) : 0ULL;

        // ---- rescan apply (repairs key2 of lane g; BEFORE insertion updates) ----
        {
            int rl = g * 48 + lane;
            bool relig = (lane < 48) && ((unsigned)(rn >> 32) == 0u)
                       && (rl != sel) && (rl != (int)idx1);
            unsigned re = relig ? (unsigned)rn : 0u;
            unsigned rmx = (unsigned)rdlane((int)wmax_u32(re), 63);
            u64 rball = __ballot(re == rmx);
            int w0 = (int)__ffsll(rball) - 1;
            u64 nk2 = rmx ? (((u64)rmx << 32) | (unsigned)(~(g * 48 + w0))) : 0ULL;
            key2 = isg ? nk2 : key2;
        }

        // ---- merge insertions: owner key updates + global candidate + S ----
        u64 cand = 0ULL;
        u64 ib = __ballot(pend != 0ULL);
        while (ib) {
            int src = (int)__ffsll(ib) - 1; ib &= ib - 1;
            u64 kfull = rdlane64(pend, src);
            int j3 = (int)~(unsigned)kfull;
            bool own = (lane == div48(j3));
            bool gt1 = kfull > key1, gt2 = kfull > key2;
            u64 ok1 = key1;
            key1 = (own && gt1) ? kfull : key1;
            key2 = own ? (gt1 ? ok1 : (gt2 ? kfull : key2)) : key2;
            cand = kfull > cand ? kfull : cand;
            S += s_elog[j3];                      // uniform broadcast read (feeds S only)
        }

        // rare slow path: column degree > 64
        if (d > 64) {
            unsigned e0full = s_meta[sel] & 0xFFFFFu;
            for (int i2 = 64 + lane; ; i2 += 64) {
                u64 p2 = 0ULL;
                if (i2 < d) {
                    int jj = (int)s_edges[e0full + i2];
                    u64 nw2 = s_keyind[jj];
                    unsigned h2 = (unsigned)(nw2 >> 32);
                    ((unsigned*)&s_keyind[jj])[1] = h2 - 1u;
                    if (h2 == 1u)
                        p2 = ((nw2 & 0xFFFFFFFFULL) << 32) | (unsigned)(~jj);
                }
                u64 ib2 = __ballot(p2 != 0ULL);
                while (ib2) {
                    int src = (int)__ffsll(ib2) - 1; ib2 &= ib2 - 1;
                    u64 kfull = rdlane64(p2, src);
                    int j3 = (int)~(unsigned)kfull;
                    bool own = (lane == div48(j3));
                    bool gt1 = kfull > key1, gt2 = kfull > key2;
                    u64 ok1 = key1;
                    key1 = (own && gt1) ? kfull : key1;
                    key2 = own ? (gt1 ? ok1 : (gt2 ? kfull : key2)) : key2;
                    cand = kfull > cand ? kfull : cand;
                    S += s_elog[j3];
                }
                if (__ballot(i2 + 64 < d) == 0ULL) break;
            }
        }

        // ---- next winner: max(k2g, insertions) ----
        u64 wcand = k2g > cand ? k2g : cand;
        unsigned nsel = ~(unsigned)wcand;
        if (nsel >= NN) nsel = 0;                 // fires only at t == NN-1

        float elog_next;
        if (cand > k2g) {
            // spec miss (rare, wave-uniform): serial reload
            unsigned m = s_meta[nsel];
            unsigned e0n = m & 0xFFFFFu;
            d = (int)(m >> 20);
            ew = (int)s_edges[e0n + (lane < d ? lane : 0)];
            elog_next = s_elog[nsel];
        } else {
            d = ds;
            ew = ews;
            elog_next = elog_spec;
        }

        // ---- background: k2g for next iteration ----
        {
            int gw2 = div48((int)nsel);
            unsigned re = (lane == gw2) ? 0u : (unsigned)(key1 >> 32);
            unsigned mx = (unsigned)rdlane((int)wmax_u32(re), 63);
            u64 ball = __ballot(re == mx);
            int w = (int)__ffsll(ball) - 1;
            unsigned lo = (unsigned)rdlane((int)(unsigned)key1, w);
            u64 k2x = mx ? (((u64)mx << 32) | lo) : 0ULL;
            u64 k2b = rdlane64(key2, gw2);
            k2g = k2x > k2b ? k2x : k2b;
        }

        // ---- S finalize (off-chain) ----
        S -= elog_sel;
        elog_sel = elog_next;
        cur_sel = nsel;
    }

    // ---- epilogue: all log_probs in parallel ----
    for (int i = lane; i < NN; i += 64) {
        unsigned si = gssel[i];
        float Si = gslog[i];
        out[si] = -logf((1.0f / s_elog[si]) * Si + 1e-10f);
    }
}

extern "C" void kernel_launch(void* const* d_in, const int* in_sizes, int n_in,
                              void* d_out, int out_size, void* d_ws, size_t ws_size,
                              hipStream_t stream) {
    const float* logits = (const float*)d_in[0];
    const float* adj    = (const float*)d_in[1];
    const float* unif   = (const float*)d_in[2];
    float* out = (float*)d_out;

    char* ws = (char*)d_ws;
    float*          rowsum = (float*)(ws + 0);                    // 12,288
    unsigned*       cnt    = (unsigned*)(ws + 16384);             // 294,912
    unsigned*       colcnt = (unsigned*)(ws + 311296);            // 12,288
    unsigned*       eoff   = (unsigned*)(ws + 323584);            // 12,292
    unsigned*       choff  = (unsigned*)(ws + 339968);            // 294,912
    unsigned short* edges  = (unsigned short*)(ws + 634880);      // 106,496
    float*          elog   = (float*)(ws + 741376);               // 12,288
    unsigned*       keyenc = (unsigned*)(ws + 753664);            // 12,288
    int*            indeg  = (int*)(ws + 765952);                 // 12,288
    float*          gslog  = (float*)(ws + 778240);               // 12,288
    unsigned*       gssel  = (unsigned*)(ws + 790528);            // ends 802,816

    rowsum_kernel<<<NN, 256, 0, stream>>>(adj, rowsum);
    cnt_kernel<<<dim3(NN / 256, NCH), 256, 0, stream>>>(adj, cnt);
    colsum_kernel<<<NN / 256, 256, 0, stream>>>(cnt, colcnt);
    scan_kernel<<<1, 64, 0, stream>>>(colcnt, eoff);
    choff_kernel<<<NN / 256, 256, 0, stream>>>(cnt, eoff, choff);
    fill2_kernel<<<dim3(NN / 256, NCH), 256, 0, stream>>>(adj, choff, edges);
    gumbel_kernel<<<NN / 256, 256, 0, stream>>>(logits, unif, rowsum, out,
                                                elog, keyenc, indeg);
    topo_kernel<<<1, 256, 0, stream>>>(elog, keyenc, indeg, eoff, edges,
                                       gslog, gssel, out);
}